// Round 8
// baseline (4727.119 us; speedup 1.0000x reference)
//
#include <hip/hip_runtime.h>
#include <cstdio>

// ============================================================================
// ROUND 22: register-safe direct-VMEM attention + pixel-major q/k/v layout.
// R21 post-mortem: 4.7 GB WRITE_SIZE = scratch spill (o arrays + 64 hoisted
// loads > 128 VGPR) -> 2091us. The direct-global idea wasn't tested fairly.
// R20 (463us) confirmed LDS-pipe-bound (model 17.4K cy/tile/CU == measured).
// This round: convqkv emits q/k/v as [b][4096 px][64 c]; attention reads
// K/V rows contiguously (1 base reg + imm offsets), P in regs, O in
// float4 oA[16]/oB[16] static-indexed, loads grouped per c4 step, zero
// main-loop barriers / K/V/P LDS. launch_bounds(256,2) -> 256 VGPR cap.
// conv_r unchanged (f stays [b][64 c][4096 px]).
// ============================================================================

// Keeps the harness-stub identifier name (unused utility).
__global__ __launch_bounds__(256) void CrossModalityPositionAttention_56556129354448_kernel(
    float* dst, float val, int n)
{
  const int i = blockIdx.x * 256 + threadIdx.x;
  if (i < n) dst[i] = val;
}

// ---------------------------------------------------------------------------
// DPP lane-shift helpers (conv halo).
__device__ __forceinline__ float dpp_left(float x) {
  return __int_as_float(__builtin_amdgcn_update_dpp(
      0, __float_as_int(x), 0x111, 0xF, 0xF, true));   // row_shr:1
}
__device__ __forceinline__ float dpp_right(float x) {
  return __int_as_float(__builtin_amdgcn_update_dpp(
      0, __float_as_int(x), 0x101, 0xF, 0xF, true));   // row_shl:1
}

#define CTROWS 18
#define CTSTR  64
#define CTSZ   (CTROWS * CTSTR)   // 1152 floats

// ---------------------------------------------------------------------------
// Fused q/k/v conv3x3 + BN + ReLU (R19 body; epilogue now writes PIXEL-MAJOR
// [b][4096][64] so attention can read K/V rows contiguously).
__global__ __launch_bounds__(256, 2) void convqkv_f32(
    const float* __restrict__ f1, const float* __restrict__ f2,
    const float* __restrict__ q_w, const float* __restrict__ q_b,
    const float* __restrict__ q_g, const float* __restrict__ q_be,
    const float* __restrict__ q_m, const float* __restrict__ q_va,
    const float* __restrict__ k_w, const float* __restrict__ k_b,
    const float* __restrict__ k_g, const float* __restrict__ k_be,
    const float* __restrict__ k_m, const float* __restrict__ k_va,
    const float* __restrict__ v_w, const float* __restrict__ v_b,
    const float* __restrict__ v_g, const float* __restrict__ v_be,
    const float* __restrict__ v_m, const float* __restrict__ v_va,
    float* __restrict__ qo, float* __restrict__ ko, float* __restrict__ vo)
{
  __shared__ float tA[2][CTSZ];
  __shared__ float tB[2][CTSZ];
  __shared__ float wlds[112];

  const int b   = blockIdx.z;
  const int co0 = blockIdx.y * 2;
  const int y0  = blockIdx.x * 16;
  const int t   = threadIdx.x;
  const int ry  = t >> 4;
  const int xg  = t & 15;
  const int x0  = xg * 4;

  float qs[2], qsh[2], ks[2], ksh[2], vs[2], vsh[2];
  #pragma unroll
  for (int cc = 0; cc < 2; ++cc) {
    const int c = co0 + cc;
    float iv;
    iv = q_g[c] * rsqrtf(q_va[c] + 1e-5f);
    qs[cc] = iv; qsh[cc] = q_b[c] * iv + q_be[c] - q_m[c] * iv;
    iv = k_g[c] * rsqrtf(k_va[c] + 1e-5f);
    ks[cc] = iv; ksh[cc] = k_b[c] * iv + k_be[c] - k_m[c] * iv;
    iv = v_g[c] * rsqrtf(v_va[c] + 1e-5f);
    vs[cc] = iv; vsh[cc] = v_b[c] * iv + v_be[c] - v_m[c] * iv;
  }

  const float* srcA = f1 + (size_t)b * 256 * 4096;
  const float* srcB = f2 + (size_t)b * 256 * 4096;

  float4 rA[2][2], rB[2][2];
  const int row0 = t >> 4;
  const int row1 = 16 + (t >> 4);
  const int grp  = t & 15;

  const int wseg = t / 18;
  const int wkk  = t - wseg * 18;
  const float* wptr = (wseg < 2) ? q_w : ((wseg < 4) ? k_w : v_w);
  const int wbase0 = (co0 + (wseg & 1)) * 256 * 9 + wkk;
  float wreg = 0.f;

  #define LOADREGS(R)                                                         \
    {                                                                         \
      _Pragma("unroll")                                                       \
      for (int s = 0; s < 2; ++s) {                                           \
        const size_t cb = (size_t)((R) * 2 + s) * 4096;                       \
        {                                                                     \
          const int gy = y0 - 1 + row0;                                       \
          float4 a = make_float4(0.f, 0.f, 0.f, 0.f);                         \
          float4 bb = make_float4(0.f, 0.f, 0.f, 0.f);                        \
          if (gy >= 0 && gy <= 63) {                                          \
            a  = *(const float4*)(srcA + cb + gy * 64 + grp * 4);             \
            bb = *(const float4*)(srcB + cb + gy * 64 + grp * 4);             \
          }                                                                   \
          rA[s][0] = a; rB[s][0] = bb;                                        \
        }                                                                     \
        if (t < 32) {                                                         \
          const int gy = y0 - 1 + row1;                                       \
          float4 a = make_float4(0.f, 0.f, 0.f, 0.f);                         \
          float4 bb = make_float4(0.f, 0.f, 0.f, 0.f);                        \
          if (gy >= 0 && gy <= 63) {                                          \
            a  = *(const float4*)(srcA + cb + gy * 64 + grp * 4);             \
            bb = *(const float4*)(srcB + cb + gy * 64 + grp * 4);             \
          }                                                                   \
          rA[s][1] = a; rB[s][1] = bb;                                        \
        }                                                                     \
      }                                                                       \
      if (t < 108) wreg = wptr[wbase0 + (R) * 18];                            \
    }

  float accQ[2][4] = {{0.f}}, accK[2][4] = {{0.f}}, accV[2][4] = {{0.f}};

  LOADREGS(0);

  for (int r = 0; r < 128; ++r) {
    __syncthreads();
    #pragma unroll
    for (int s = 0; s < 2; ++s) {
      *(float4*)(&tA[s][row0 * CTSTR + grp * 4]) = rA[s][0];
      *(float4*)(&tB[s][row0 * CTSTR + grp * 4]) = rB[s][0];
      if (t < 32) {
        *(float4*)(&tA[s][row1 * CTSTR + grp * 4]) = rA[s][1];
        *(float4*)(&tB[s][row1 * CTSTR + grp * 4]) = rB[s][1];
      }
    }
    if (t < 108) wlds[t] = wreg;
    __syncthreads();
    if (r < 127) LOADREGS(r + 1);

    #pragma unroll
    for (int s = 0; s < 2; ++s) {
      #pragma unroll
      for (int ky = 0; ky < 3; ++ky) {
        const float4 a4 = *(const float4*)(&tA[s][(ry + ky) * CTSTR + x0]);
        const float4 b4 = *(const float4*)(&tB[s][(ry + ky) * CTSTR + x0]);
        const float ca[6] = {dpp_left(a4.w), a4.x, a4.y, a4.z, a4.w, dpp_right(a4.x)};
        const float cb[6] = {dpp_left(b4.w), b4.x, b4.y, b4.z, b4.w, dpp_right(b4.x)};
        #pragma unroll
        for (int cc = 0; cc < 2; ++cc) {
          const int wb = cc * 18 + s * 9 + ky * 3;
          const float q0 = wlds[wb],      q1 = wlds[wb + 1],      q2 = wlds[wb + 2];
          const float k0 = wlds[36 + wb], k1 = wlds[36 + wb + 1], k2 = wlds[36 + wb + 2];
          const float v0 = wlds[72 + wb], v1 = wlds[72 + wb + 1], v2 = wlds[72 + wb + 2];
          #pragma unroll
          for (int px = 0; px < 4; ++px) {
            accQ[cc][px] += cb[px] * q0 + cb[px + 1] * q1 + cb[px + 2] * q2;
            accK[cc][px] += ca[px] * k0 + ca[px + 1] * k1 + ca[px + 2] * k2;
            accV[cc][px] += ca[px] * v0 + ca[px + 1] * v1 + ca[px + 2] * v2;
          }
        }
      }
    }
  }

  // epilogue: BN + ReLU; PIXEL-MAJOR stores: out[(b*4096 + px)*64 + co]
  const size_t pb = (size_t)b * 4096 + (size_t)(y0 + ry) * 64 + x0;
  #pragma unroll
  for (int px = 0; px < 4; ++px) {
    const size_t o8 = (pb + px) * 64 + co0;
    float2 o2;
    o2.x = fmaxf(accQ[0][px] * qs[0] + qsh[0], 0.f);
    o2.y = fmaxf(accQ[1][px] * qs[1] + qsh[1], 0.f);
    *(float2*)(qo + o8) = o2;
    o2.x = fmaxf(accK[0][px] * ks[0] + ksh[0], 0.f);
    o2.y = fmaxf(accK[1][px] * ks[1] + ksh[1], 0.f);
    *(float2*)(ko + o8) = o2;
    o2.x = fmaxf(accV[0][px] * vs[0] + vsh[0], 0.f);
    o2.y = fmaxf(accV[1][px] * vs[1] + vsh[1], 0.f);
    *(float2*)(vo + o8) = o2;
  }
}

// ---------------------------------------------------------------------------
// Flash attention, fp32. q,k,v PIXEL-MAJOR [b][4096][64]; f [b][64][4096].
// 32 queries/block, grid 512 = 2 blocks/CU. b = (lin&7)>>1 pins batch per
// XCD-pair. Thread (mg=t&15, ng=t>>4): m-cols 4mg+{0..3}, rows 2ng+{0,1}.
// K/V read direct from global: thread's 4 rows are contiguous 256B; all 64
// loads/tile = one base + imm offsets. P in regs; O in float4 oA/oB[16]
// (static indices only). Cross-mg shfl reduce + predicated stores at end.
__global__ __launch_bounds__(256, 2) void attention_flash_f32(
    const float* __restrict__ q, const float* __restrict__ k,
    const float* __restrict__ v, float* __restrict__ f)
{
  __shared__ float qt[32 * 68];   // Q rows [n][c], stride 68 (8.7 KB)

  const int lin = blockIdx.x;
  const int b  = (lin & 7) >> 1;
  const int nb = ((lin >> 3) << 1) | (lin & 1);
  const int n0 = nb * 32;

  const int t = threadIdx.x;
  const int mg = t & 15;
  const int ng = t >> 4;

  const float* qb = q + (size_t)b * 4096 * 64;
  const float* kb = k + (size_t)b * 4096 * 64;
  const float* vb = v + (size_t)b * 4096 * 64;

  // stage Q rows n0..n0+31 (coalesced; row-major [n][c])
  {
    const int row = t >> 3;
    const int c8 = (t & 7) * 8;
    const float4 a0 = *(const float4*)(qb + (size_t)(n0 + row) * 64 + c8);
    const float4 a1 = *(const float4*)(qb + (size_t)(n0 + row) * 64 + c8 + 4);
    *(float4*)(qt + row * 68 + c8)     = a0;
    *(float4*)(qt + row * 68 + c8 + 4) = a1;
  }
  __syncthreads();

  float4 oA[16], oB[16];
  #pragma unroll
  for (int i = 0; i < 16; ++i) {
    oA[i] = make_float4(0.f, 0.f, 0.f, 0.f);
    oB[i] = make_float4(0.f, 0.f, 0.f, 0.f);
  }
  float m0r = -1e30f, m1r = -1e30f, l0 = 0.f, l1 = 0.f;

  const float* qrow0 = qt + (2 * ng + 0) * 68;
  const float* qrow1 = qt + (2 * ng + 1) * 68;

  for (int tile = 0; tile < 64; ++tile) {
    const float* kp = kb + ((size_t)tile * 64 + 4 * mg) * 64;
    const float* vp = vb + ((size_t)tile * 64 + 4 * mg) * 64;

    // ---- QK: s[i][j] = Q[row_i] . K[4mg+j]  (rows contiguous, imm offsets)
    float s00 = 0.f, s01 = 0.f, s02 = 0.f, s03 = 0.f;
    float s10 = 0.f, s11 = 0.f, s12 = 0.f, s13 = 0.f;
    #pragma unroll
    for (int c4 = 0; c4 < 16; ++c4) {
      const float4 k0 = *(const float4*)(kp +       c4 * 4);
      const float4 k1 = *(const float4*)(kp +  64 + c4 * 4);
      const float4 k2 = *(const float4*)(kp + 128 + c4 * 4);
      const float4 k3 = *(const float4*)(kp + 192 + c4 * 4);
      const float4 qa = *(const float4*)(qrow0 + c4 * 4);
      const float4 qc = *(const float4*)(qrow1 + c4 * 4);
      s00 = fmaf(qa.w, k0.w, fmaf(qa.z, k0.z, fmaf(qa.y, k0.y, fmaf(qa.x, k0.x, s00))));
      s01 = fmaf(qa.w, k1.w, fmaf(qa.z, k1.z, fmaf(qa.y, k1.y, fmaf(qa.x, k1.x, s01))));
      s02 = fmaf(qa.w, k2.w, fmaf(qa.z, k2.z, fmaf(qa.y, k2.y, fmaf(qa.x, k2.x, s02))));
      s03 = fmaf(qa.w, k3.w, fmaf(qa.z, k3.z, fmaf(qa.y, k3.y, fmaf(qa.x, k3.x, s03))));
      s10 = fmaf(qc.w, k0.w, fmaf(qc.z, k0.z, fmaf(qc.y, k0.y, fmaf(qc.x, k0.x, s10))));
      s11 = fmaf(qc.w, k1.w, fmaf(qc.z, k1.z, fmaf(qc.y, k1.y, fmaf(qc.x, k1.x, s11))));
      s12 = fmaf(qc.w, k2.w, fmaf(qc.z, k2.z, fmaf(qc.y, k2.y, fmaf(qc.x, k2.x, s12))));
      s13 = fmaf(qc.w, k3.w, fmaf(qc.z, k3.z, fmaf(qc.y, k3.y, fmaf(qc.x, k3.x, s13))));
    }

    // ---- online softmax (across 16 mg-lanes)
    float rm0 = fmaxf(fmaxf(s00, s01), fmaxf(s02, s03));
    rm0 = fmaxf(rm0, __shfl_xor(rm0, 1));
    rm0 = fmaxf(rm0, __shfl_xor(rm0, 2));
    rm0 = fmaxf(rm0, __shfl_xor(rm0, 4));
    rm0 = fmaxf(rm0, __shfl_xor(rm0, 8));
    float rm1 = fmaxf(fmaxf(s10, s11), fmaxf(s12, s13));
    rm1 = fmaxf(rm1, __shfl_xor(rm1, 1));
    rm1 = fmaxf(rm1, __shfl_xor(rm1, 2));
    rm1 = fmaxf(rm1, __shfl_xor(rm1, 4));
    rm1 = fmaxf(rm1, __shfl_xor(rm1, 8));

    const float mn0 = fmaxf(m0r, rm0);
    const float mn1 = fmaxf(m1r, rm1);
    const float al0 = __expf(m0r - mn0);
    const float al1 = __expf(m1r - mn1);
    m0r = mn0; m1r = mn1;

    const float p00 = __expf(s00 - mn0), p01 = __expf(s01 - mn0);
    const float p02 = __expf(s02 - mn0), p03 = __expf(s03 - mn0);
    const float p10 = __expf(s10 - mn1), p11 = __expf(s11 - mn1);
    const float p12 = __expf(s12 - mn1), p13 = __expf(s13 - mn1);

    float rs0 = p00 + p01 + p02 + p03;
    rs0 += __shfl_xor(rs0, 1);
    rs0 += __shfl_xor(rs0, 2);
    rs0 += __shfl_xor(rs0, 4);
    rs0 += __shfl_xor(rs0, 8);
    float rs1 = p10 + p11 + p12 + p13;
    rs1 += __shfl_xor(rs1, 1);
    rs1 += __shfl_xor(rs1, 2);
    rs1 += __shfl_xor(rs1, 4);
    rs1 += __shfl_xor(rs1, 8);
    l0 = al0 * l0 + rs0;
    l1 = al1 * l1 + rs1;

    // ---- rescale O
    #pragma unroll
    for (int i = 0; i < 16; ++i) {
      oA[i].x *= al0; oA[i].y *= al0; oA[i].z *= al0; oA[i].w *= al0;
      oB[i].x *= al1; oB[i].y *= al1; oB[i].z *= al1; oB[i].w *= al1;
    }

    // ---- PV: o[n][4c4..] += sum_j p[n][j] * V[4mg+j][c]
    #pragma unroll
    for (int c4 = 0; c4 < 16; ++c4) {
      const float4 v0 = *(const float4*)(vp +       c4 * 4);
      const float4 v1 = *(const float4*)(vp +  64 + c4 * 4);
      const float4 v2 = *(const float4*)(vp + 128 + c4 * 4);
      const float4 v3 = *(const float4*)(vp + 192 + c4 * 4);
      oA[c4].x = fmaf(p03, v3.x, fmaf(p02, v2.x, fmaf(p01, v1.x, fmaf(p00, v0.x, oA[c4].x))));
      oA[c4].y = fmaf(p03, v3.y, fmaf(p02, v2.y, fmaf(p01, v1.y, fmaf(p00, v0.y, oA[c4].y))));
      oA[c4].z = fmaf(p03, v3.z, fmaf(p02, v2.z, fmaf(p01, v1.z, fmaf(p00, v0.z, oA[c4].z))));
      oA[c4].w = fmaf(p03, v3.w, fmaf(p02, v2.w, fmaf(p01, v1.w, fmaf(p00, v0.w, oA[c4].w))));
      oB[c4].x = fmaf(p13, v3.x, fmaf(p12, v2.x, fmaf(p11, v1.x, fmaf(p10, v0.x, oB[c4].x))));
      oB[c4].y = fmaf(p13, v3.y, fmaf(p12, v2.y, fmaf(p11, v1.y, fmaf(p10, v0.y, oB[c4].y))));
      oB[c4].z = fmaf(p13, v3.z, fmaf(p12, v2.z, fmaf(p11, v1.z, fmaf(p10, v0.z, oB[c4].z))));
      oB[c4].w = fmaf(p13, v3.w, fmaf(p12, v2.w, fmaf(p11, v1.w, fmaf(p10, v0.w, oB[c4].w))));
    }
  }

  // ---- cross-mg reduce (16 lanes, xor butterfly -> all lanes hold sums)
  #pragma unroll
  for (int i = 0; i < 16; ++i) {
    oA[i].x += __shfl_xor(oA[i].x, 1); oA[i].x += __shfl_xor(oA[i].x, 2);
    oA[i].x += __shfl_xor(oA[i].x, 4); oA[i].x += __shfl_xor(oA[i].x, 8);
    oA[i].y += __shfl_xor(oA[i].y, 1); oA[i].y += __shfl_xor(oA[i].y, 2);
    oA[i].y += __shfl_xor(oA[i].y, 4); oA[i].y += __shfl_xor(oA[i].y, 8);
    oA[i].z += __shfl_xor(oA[i].z, 1); oA[i].z += __shfl_xor(oA[i].z, 2);
    oA[i].z += __shfl_xor(oA[i].z, 4); oA[i].z += __shfl_xor(oA[i].z, 8);
    oA[i].w += __shfl_xor(oA[i].w, 1); oA[i].w += __shfl_xor(oA[i].w, 2);
    oA[i].w += __shfl_xor(oA[i].w, 4); oA[i].w += __shfl_xor(oA[i].w, 8);
    oB[i].x += __shfl_xor(oB[i].x, 1); oB[i].x += __shfl_xor(oB[i].x, 2);
    oB[i].x += __shfl_xor(oB[i].x, 4); oB[i].x += __shfl_xor(oB[i].x, 8);
    oB[i].y += __shfl_xor(oB[i].y, 1); oB[i].y += __shfl_xor(oB[i].y, 2);
    oB[i].y += __shfl_xor(oB[i].y, 4); oB[i].y += __shfl_xor(oB[i].y, 8);
    oB[i].z += __shfl_xor(oB[i].z, 1); oB[i].z += __shfl_xor(oB[i].z, 2);
    oB[i].z += __shfl_xor(oB[i].z, 4); oB[i].z += __shfl_xor(oB[i].z, 8);
    oB[i].w += __shfl_xor(oB[i].w, 1); oB[i].w += __shfl_xor(oB[i].w, 2);
    oB[i].w += __shfl_xor(oB[i].w, 4); oB[i].w += __shfl_xor(oB[i].w, 8);
  }
  const float inv0 = 1.f / l0;
  const float inv1 = 1.f / l1;

  // ---- predicated direct stores: lane mg==i owns c rows 4i..4i+3.
  // f layout [b][64 c][4096 n] (unchanged for conv_r): float2 at (c, n0+2ng).
  #pragma unroll
  for (int i = 0; i < 16; ++i) {
    if (mg == i) {
      float* fc = f + ((size_t)b * 64 + 4 * i) * 4096 + n0 + 2 * ng;
      *(float2*)(fc + 0 * 4096) = make_float2(oA[i].x * inv0, oB[i].x * inv1);
      *(float2*)(fc + 1 * 4096) = make_float2(oA[i].y * inv0, oB[i].y * inv1);
      *(float2*)(fc + 2 * 4096) = make_float2(oA[i].z * inv0, oB[i].z * inv1);
      *(float2*)(fc + 3 * 4096) = make_float2(oA[i].w * inv0, oB[i].w * inv1);
    }
  }
}

// ---------------------------------------------------------------------------
// conv_r (unchanged from R19; fin is [b][64 c][4096 px]).
__global__ __launch_bounds__(256, 4) void conv_r_f32(
    const float* __restrict__ fin, const float* __restrict__ w,
    const float* __restrict__ bi, const float* __restrict__ g,
    const float* __restrict__ be, const float* __restrict__ mu,
    const float* __restrict__ va, const float* __restrict__ res,
    float* __restrict__ out)
{
  __shared__ float tA[2][CTSZ];
  __shared__ float wlds[80];

  const int b   = blockIdx.z;
  const int co0 = blockIdx.y * 4;
  const int y0  = blockIdx.x * 16;
  const int t   = threadIdx.x;
  const int ry  = t >> 4;
  const int xg  = t & 15;
  const int x0  = xg * 4;

  float sc[4], sh[4];
  #pragma unroll
  for (int cc = 0; cc < 4; ++cc) {
    const int c = co0 + cc;
    const float iv = g[c] * rsqrtf(va[c] + 1e-5f);
    sc[cc] = iv; sh[cc] = bi[c] * iv + be[c] - mu[c] * iv;
  }

  const float* srcA = fin + (size_t)b * 64 * 4096;
  float4 rA[2][2];
  const int row0 = t >> 4;
  const int row1 = 16 + (t >> 4);
  const int grp  = t & 15;

  const int wseg = t / 18;
  const int wkk  = t - wseg * 18;
  const int wbase0 = (co0 + wseg) * 64 * 9 + wkk;
  float wreg = 0.f;

  #define LOADR(R)                                                            \
    {                                                                         \
      _Pragma("unroll")                                                       \
      for (int s = 0; s < 2; ++s) {                                           \
        const size_t cb = (size_t)((R) * 2 + s) * 4096;                       \
        {                                                                     \
          const int gy = y0 - 1 + row0;                                       \
          float4 a = make_float4(0.f, 0.f, 0.f, 0.f);                         \
          if (gy >= 0 && gy <= 63)                                            \
            a = *(const float4*)(srcA + cb + gy * 64 + grp * 4);              \
          rA[s][0] = a;                                                       \
        }                                                                     \
        if (t < 32) {                                                         \
          const int gy = y0 - 1 + row1;                                       \
          float4 a = make_float4(0.f, 0.f, 0.f, 0.f);                         \
          if (gy >= 0 && gy <= 63)                                            \
            a = *(const float4*)(srcA + cb + gy * 64 + grp * 4);              \
          rA[s][1] = a;                                                       \
        }                                                                     \
      }                                                                       \
      if (t < 72) wreg = w[wbase0 + (R) * 18];                                \
    }

  float acc[4][4] = {{0.f}};
  LOADR(0);

  for (int r = 0; r < 32; ++r) {
    __syncthreads();
    #pragma unroll
    for (int s = 0; s < 2; ++s) {
      *(float4*)(&tA[s][row0 * CTSTR + grp * 4]) = rA[s][0];
      if (t < 32)
        *(float4*)(&tA[s][row1 * CTSTR + grp * 4]) = rA[s][1];
    }
    if (t < 72) wlds[t] = wreg;
    __syncthreads();
    if (r < 31) LOADR(r + 1);

    #pragma unroll
    for (int s = 0; s < 2; ++s) {
      #pragma unroll
      for (int ky = 0; ky < 3; ++ky) {
        const float4 a4 = *(const float4*)(&tA[s][(ry + ky) * CTSTR + x0]);
        const float ca[6] = {dpp_left(a4.w), a4.x, a4.y, a4.z, a4.w, dpp_right(a4.x)};
        #pragma unroll
        for (int cc = 0; cc < 4; ++cc) {
          const int wb = cc * 18 + s * 9 + ky * 3;
          const float w0 = wlds[wb], w1 = wlds[wb + 1], w2 = wlds[wb + 2];
          #pragma unroll
          for (int px = 0; px < 4; ++px)
            acc[cc][px] += ca[px] * w0 + ca[px + 1] * w1 + ca[px + 2] * w2;
        }
      }
    }
  }

  const size_t ob = ((size_t)b * 256 + co0) * 4096 + (size_t)(y0 + ry) * 64 + x0;
  #pragma unroll
  for (int cc = 0; cc < 4; ++cc) {
    const float4 rv = *(const float4*)(res + ob + (size_t)cc * 4096);
    float4 o;
    o.x = rv.x + fmaxf(acc[cc][0] * sc[cc] + sh[cc], 0.f);
    o.y = rv.y + fmaxf(acc[cc][1] * sc[cc] + sh[cc], 0.f);
    o.z = rv.z + fmaxf(acc[cc][2] * sc[cc] + sh[cc], 0.f);
    o.w = rv.w + fmaxf(acc[cc][3] * sc[cc] + sh[cc], 0.f);
    *(float4*)(out + ob + (size_t)cc * 4096) = o;
  }
}

// ---------------------------------------------------------------------------
extern "C" void kernel_launch(void* const* d_in, const int* in_sizes, int n_in,
                              void* d_out, int out_size, void* d_ws, size_t ws_size,
                              hipStream_t stream) {
  const float* f1 = (const float*)d_in[0];
  const float* f2 = (const float*)d_in[1];
  const float* qw = (const float*)d_in[2];  const float* qb = (const float*)d_in[3];
  const float* qg = (const float*)d_in[4];  const float* qbe = (const float*)d_in[5];
  const float* qm = (const float*)d_in[6];  const float* qv = (const float*)d_in[7];
  const float* kw = (const float*)d_in[8];  const float* kb = (const float*)d_in[9];
  const float* kg = (const float*)d_in[10]; const float* kbe = (const float*)d_in[11];
  const float* km = (const float*)d_in[12]; const float* kv = (const float*)d_in[13];
  const float* vw = (const float*)d_in[14]; const float* vb = (const float*)d_in[15];
  const float* vg = (const float*)d_in[16]; const float* vbe = (const float*)d_in[17];
  const float* vm = (const float*)d_in[18]; const float* vv = (const float*)d_in[19];
  const float* rw = (const float*)d_in[20]; const float* rb = (const float*)d_in[21];
  const float* rg = (const float*)d_in[22]; const float* rbe = (const float*)d_in[23];
  const float* rm = (const float*)d_in[24]; const float* rv = (const float*)d_in[25];

  hipStreamCaptureStatus cap = hipStreamCaptureStatusNone;
  unsigned long long capid = 0;
  const hipError_t ce = hipStreamGetCaptureInfo(stream, &cap, &capid);
  const bool capturing = (ce == hipSuccess) && (cap != hipStreamCaptureStatusNone);

  // Workspace: q,k,v (pixel-major) + f (channel-major), 4 MB each.
  const size_t SZ1 = (size_t)4 * 64 * 4096 * 4;
  float* qp = (float*)d_ws;
  float* kp = (float*)((char*)d_ws + SZ1);
  float* vp = (float*)((char*)d_ws + 2 * SZ1);
  float* fp = (float*)((char*)d_ws + 3 * SZ1);

  convqkv_f32<<<dim3(4, 32, 4), 256, 0, stream>>>(
      f1, f2,
      qw, qb, qg, qbe, qm, qv,
      kw, kb, kg, kbe, km, kv,
      vw, vb, vg, vbe, vm, vv,
      qp, kp, vp);
  attention_flash_f32<<<dim3(512), 256, 0, stream>>>(qp, kp, vp, fp);
  conv_r_f32<<<dim3(4, 64, 4), 256, 0, stream>>>(fp, rw, rb, rg, rbe, rm, rv,
                                                 f1, (float*)d_out);

  if (!capturing) {
    const hipError_t le = hipGetLastError();
    const hipError_t se = hipStreamSynchronize(stream);
    float h[4] = {0, 0, 0, 0};
    (void)hipMemcpy(h, d_out, 16, hipMemcpyDeviceToHost);
    fprintf(stderr,
        "ATHENA_R22 pixel-major-attn le=%d sync=%d out=[%g %g %g %g]\n",
        (int)le, (int)se, h[0], h[1], h[2], h[3]);
    fflush(stderr);
  }
}

// Round 9
// 1781.170 us; speedup vs baseline: 2.6539x; 2.6539x over previous
//
#include <hip/hip_runtime.h>
#include <cstdio>

// ============================================================================
// ROUND 23: attention = direct-VMEM K/V + 8-float O + P-through-LDS.
// R21/R22 post-mortem: both spilled (VGPR pinned 128, 5-10 GB scratch traffic
// -> 2-3.4ms). A 128-float per-thread O does not survive regalloc. R20 (463us)
// is LDS-pipe-bound (~2400 cy/wave/tile LDS vs ~2200 FMA).
// This round: thread tile back to o[2][4] (8 floats, scalars only), K/V read
// direct from global (pixel-major, coalesced 256B, L1/L2-resident), P
// exchanged via small LDS tile (2 b128 W + 32 broadcast b128 R per tile).
// LDS/wave/tile ~790cy < FMA ~2200cy; VMEM 128 b128 coalesced. ~70 VGPR.
// 2 barriers/tile, 512 blocks = 2/CU. FMA order == R20 -> same absmax.
// convqkv (pixel-major epilogue) + conv_r unchanged from R22 (verified).
// ============================================================================

// Keeps the harness-stub identifier name (unused utility).
__global__ __launch_bounds__(256) void CrossModalityPositionAttention_56556129354448_kernel(
    float* dst, float val, int n)
{
  const int i = blockIdx.x * 256 + threadIdx.x;
  if (i < n) dst[i] = val;
}

// ---------------------------------------------------------------------------
// DPP lane-shift helpers (conv halo).
__device__ __forceinline__ float dpp_left(float x) {
  return __int_as_float(__builtin_amdgcn_update_dpp(
      0, __float_as_int(x), 0x111, 0xF, 0xF, true));   // row_shr:1
}
__device__ __forceinline__ float dpp_right(float x) {
  return __int_as_float(__builtin_amdgcn_update_dpp(
      0, __float_as_int(x), 0x101, 0xF, 0xF, true));   // row_shl:1
}

#define CTROWS 18
#define CTSTR  64
#define CTSZ   (CTROWS * CTSTR)   // 1152 floats

// ---------------------------------------------------------------------------
// Fused q/k/v conv3x3 + BN + ReLU (R22: pixel-major [b][4096][64] outputs).
__global__ __launch_bounds__(256, 2) void convqkv_f32(
    const float* __restrict__ f1, const float* __restrict__ f2,
    const float* __restrict__ q_w, const float* __restrict__ q_b,
    const float* __restrict__ q_g, const float* __restrict__ q_be,
    const float* __restrict__ q_m, const float* __restrict__ q_va,
    const float* __restrict__ k_w, const float* __restrict__ k_b,
    const float* __restrict__ k_g, const float* __restrict__ k_be,
    const float* __restrict__ k_m, const float* __restrict__ k_va,
    const float* __restrict__ v_w, const float* __restrict__ v_b,
    const float* __restrict__ v_g, const float* __restrict__ v_be,
    const float* __restrict__ v_m, const float* __restrict__ v_va,
    float* __restrict__ qo, float* __restrict__ ko, float* __restrict__ vo)
{
  __shared__ float tA[2][CTSZ];
  __shared__ float tB[2][CTSZ];
  __shared__ float wlds[112];

  const int b   = blockIdx.z;
  const int co0 = blockIdx.y * 2;
  const int y0  = blockIdx.x * 16;
  const int t   = threadIdx.x;
  const int ry  = t >> 4;
  const int xg  = t & 15;
  const int x0  = xg * 4;

  float qs[2], qsh[2], ks[2], ksh[2], vs[2], vsh[2];
  #pragma unroll
  for (int cc = 0; cc < 2; ++cc) {
    const int c = co0 + cc;
    float iv;
    iv = q_g[c] * rsqrtf(q_va[c] + 1e-5f);
    qs[cc] = iv; qsh[cc] = q_b[c] * iv + q_be[c] - q_m[c] * iv;
    iv = k_g[c] * rsqrtf(k_va[c] + 1e-5f);
    ks[cc] = iv; ksh[cc] = k_b[c] * iv + k_be[c] - k_m[c] * iv;
    iv = v_g[c] * rsqrtf(v_va[c] + 1e-5f);
    vs[cc] = iv; vsh[cc] = v_b[c] * iv + v_be[c] - v_m[c] * iv;
  }

  const float* srcA = f1 + (size_t)b * 256 * 4096;
  const float* srcB = f2 + (size_t)b * 256 * 4096;

  float4 rA[2][2], rB[2][2];
  const int row0 = t >> 4;
  const int row1 = 16 + (t >> 4);
  const int grp  = t & 15;

  const int wseg = t / 18;
  const int wkk  = t - wseg * 18;
  const float* wptr = (wseg < 2) ? q_w : ((wseg < 4) ? k_w : v_w);
  const int wbase0 = (co0 + (wseg & 1)) * 256 * 9 + wkk;
  float wreg = 0.f;

  #define LOADREGS(R)                                                         \
    {                                                                         \
      _Pragma("unroll")                                                       \
      for (int s = 0; s < 2; ++s) {                                           \
        const size_t cb = (size_t)((R) * 2 + s) * 4096;                       \
        {                                                                     \
          const int gy = y0 - 1 + row0;                                       \
          float4 a = make_float4(0.f, 0.f, 0.f, 0.f);                         \
          float4 bb = make_float4(0.f, 0.f, 0.f, 0.f);                        \
          if (gy >= 0 && gy <= 63) {                                          \
            a  = *(const float4*)(srcA + cb + gy * 64 + grp * 4);             \
            bb = *(const float4*)(srcB + cb + gy * 64 + grp * 4);             \
          }                                                                   \
          rA[s][0] = a; rB[s][0] = bb;                                        \
        }                                                                     \
        if (t < 32) {                                                         \
          const int gy = y0 - 1 + row1;                                       \
          float4 a = make_float4(0.f, 0.f, 0.f, 0.f);                         \
          float4 bb = make_float4(0.f, 0.f, 0.f, 0.f);                        \
          if (gy >= 0 && gy <= 63) {                                          \
            a  = *(const float4*)(srcA + cb + gy * 64 + grp * 4);             \
            bb = *(const float4*)(srcB + cb + gy * 64 + grp * 4);             \
          }                                                                   \
          rA[s][1] = a; rB[s][1] = bb;                                        \
        }                                                                     \
      }                                                                       \
      if (t < 108) wreg = wptr[wbase0 + (R) * 18];                            \
    }

  float accQ[2][4] = {{0.f}}, accK[2][4] = {{0.f}}, accV[2][4] = {{0.f}};

  LOADREGS(0);

  for (int r = 0; r < 128; ++r) {
    __syncthreads();
    #pragma unroll
    for (int s = 0; s < 2; ++s) {
      *(float4*)(&tA[s][row0 * CTSTR + grp * 4]) = rA[s][0];
      *(float4*)(&tB[s][row0 * CTSTR + grp * 4]) = rB[s][0];
      if (t < 32) {
        *(float4*)(&tA[s][row1 * CTSTR + grp * 4]) = rA[s][1];
        *(float4*)(&tB[s][row1 * CTSTR + grp * 4]) = rB[s][1];
      }
    }
    if (t < 108) wlds[t] = wreg;
    __syncthreads();
    if (r < 127) LOADREGS(r + 1);

    #pragma unroll
    for (int s = 0; s < 2; ++s) {
      #pragma unroll
      for (int ky = 0; ky < 3; ++ky) {
        const float4 a4 = *(const float4*)(&tA[s][(ry + ky) * CTSTR + x0]);
        const float4 b4 = *(const float4*)(&tB[s][(ry + ky) * CTSTR + x0]);
        const float ca[6] = {dpp_left(a4.w), a4.x, a4.y, a4.z, a4.w, dpp_right(a4.x)};
        const float cb[6] = {dpp_left(b4.w), b4.x, b4.y, b4.z, b4.w, dpp_right(b4.x)};
        #pragma unroll
        for (int cc = 0; cc < 2; ++cc) {
          const int wb = cc * 18 + s * 9 + ky * 3;
          const float q0 = wlds[wb],      q1 = wlds[wb + 1],      q2 = wlds[wb + 2];
          const float k0 = wlds[36 + wb], k1 = wlds[36 + wb + 1], k2 = wlds[36 + wb + 2];
          const float v0 = wlds[72 + wb], v1 = wlds[72 + wb + 1], v2 = wlds[72 + wb + 2];
          #pragma unroll
          for (int px = 0; px < 4; ++px) {
            accQ[cc][px] += cb[px] * q0 + cb[px + 1] * q1 + cb[px + 2] * q2;
            accK[cc][px] += ca[px] * k0 + ca[px + 1] * k1 + ca[px + 2] * k2;
            accV[cc][px] += ca[px] * v0 + ca[px + 1] * v1 + ca[px + 2] * v2;
          }
        }
      }
    }
  }

  // epilogue: BN + ReLU; PIXEL-MAJOR stores: out[(b*4096 + px)*64 + co]
  const size_t pb = (size_t)b * 4096 + (size_t)(y0 + ry) * 64 + x0;
  #pragma unroll
  for (int px = 0; px < 4; ++px) {
    const size_t o8 = (pb + px) * 64 + co0;
    float2 o2;
    o2.x = fmaxf(accQ[0][px] * qs[0] + qsh[0], 0.f);
    o2.y = fmaxf(accQ[1][px] * qs[1] + qsh[1], 0.f);
    *(float2*)(qo + o8) = o2;
    o2.x = fmaxf(accK[0][px] * ks[0] + ksh[0], 0.f);
    o2.y = fmaxf(accK[1][px] * ks[1] + ksh[1], 0.f);
    *(float2*)(ko + o8) = o2;
    o2.x = fmaxf(accV[0][px] * vs[0] + vsh[0], 0.f);
    o2.y = fmaxf(accV[1][px] * vs[1] + vsh[1], 0.f);
    *(float2*)(vo + o8) = o2;
  }
}

// ---------------------------------------------------------------------------
// Flash attention, fp32. q,k,v PIXEL-MAJOR [b][4096][64]; f [b][64][4096].
// 32 queries/block, grid 512 = 2 blocks/CU. b = (lin&7)>>1 pins batch per
// XCD-pair. Thread (mg=t&15, ng=t>>4): QK m-cols 4mg+{0..3}, rows 2ng+{0,1};
// PV c-cols 4mg+{0..3}. o[2][4] = 8 floats (scalars, never spills).
// K/V direct VMEM (coalesced); P exchanged via LDS [32][68]; 2 barriers/tile.
__global__ __launch_bounds__(256, 2) void attention_flash_f32(
    const float* __restrict__ q, const float* __restrict__ k,
    const float* __restrict__ v, float* __restrict__ f)
{
  __shared__ float smem[2176 * 2];   // qt [32][68] | pt [32][68]; 17408 B
  float* qt = smem;
  float* pt = smem + 2176;

  const int lin = blockIdx.x;
  const int b  = (lin & 7) >> 1;
  const int nb = ((lin >> 3) << 1) | (lin & 1);
  const int n0 = nb * 32;

  const int t = threadIdx.x;
  const int mg = t & 15;
  const int ng = t >> 4;

  const float* qb = q + (size_t)b * 4096 * 64;
  const float* kb = k + (size_t)b * 4096 * 64;
  const float* vb = v + (size_t)b * 4096 * 64;

  // stage Q rows n0..n0+31, row-major [n][c], stride 68 (coalesced)
  {
    const int row = t >> 3;
    const int c8 = (t & 7) * 8;
    const float4 a0 = *(const float4*)(qb + (size_t)(n0 + row) * 64 + c8);
    const float4 a1 = *(const float4*)(qb + (size_t)(n0 + row) * 64 + c8 + 4);
    *(float4*)(qt + row * 68 + c8)     = a0;
    *(float4*)(qt + row * 68 + c8 + 4) = a1;
  }
  __syncthreads();

  float4 o0 = make_float4(0.f, 0.f, 0.f, 0.f);   // rows 2ng, c-cols 4mg+j
  float4 o1 = make_float4(0.f, 0.f, 0.f, 0.f);   // rows 2ng+1
  float m0r = -1e30f, m1r = -1e30f, l0 = 0.f, l1 = 0.f;

  const float* qrow0 = qt + (2 * ng + 0) * 68;
  const float* qrow1 = qt + (2 * ng + 1) * 68;
  float* prow0 = pt + (2 * ng + 0) * 68;
  float* prow1 = pt + (2 * ng + 1) * 68;

  for (int tile = 0; tile < 64; ++tile) {
    const float* kp  = kb + ((size_t)tile * 64 + 4 * mg) * 64;  // K rows 4mg..
    const float* vpt = vb + (size_t)tile * 4096 + 4 * mg;       // V[m][4mg..]

    // ---- QK: s[i][j] = Q[row_i] . K[4mg+j]  (rows contiguous, imm offsets)
    float s00 = 0.f, s01 = 0.f, s02 = 0.f, s03 = 0.f;
    float s10 = 0.f, s11 = 0.f, s12 = 0.f, s13 = 0.f;
    #pragma unroll
    for (int c4 = 0; c4 < 16; ++c4) {
      const float4 k0 = *(const float4*)(kp +       c4 * 4);
      const float4 k1 = *(const float4*)(kp +  64 + c4 * 4);
      const float4 k2 = *(const float4*)(kp + 128 + c4 * 4);
      const float4 k3 = *(const float4*)(kp + 192 + c4 * 4);
      const float4 qa = *(const float4*)(qrow0 + c4 * 4);
      const float4 qc = *(const float4*)(qrow1 + c4 * 4);
      s00 = fmaf(qa.w, k0.w, fmaf(qa.z, k0.z, fmaf(qa.y, k0.y, fmaf(qa.x, k0.x, s00))));
      s01 = fmaf(qa.w, k1.w, fmaf(qa.z, k1.z, fmaf(qa.y, k1.y, fmaf(qa.x, k1.x, s01))));
      s02 = fmaf(qa.w, k2.w, fmaf(qa.z, k2.z, fmaf(qa.y, k2.y, fmaf(qa.x, k2.x, s02))));
      s03 = fmaf(qa.w, k3.w, fmaf(qa.z, k3.z, fmaf(qa.y, k3.y, fmaf(qa.x, k3.x, s03))));
      s10 = fmaf(qc.w, k0.w, fmaf(qc.z, k0.z, fmaf(qc.y, k0.y, fmaf(qc.x, k0.x, s10))));
      s11 = fmaf(qc.w, k1.w, fmaf(qc.z, k1.z, fmaf(qc.y, k1.y, fmaf(qc.x, k1.x, s11))));
      s12 = fmaf(qc.w, k2.w, fmaf(qc.z, k2.z, fmaf(qc.y, k2.y, fmaf(qc.x, k2.x, s12))));
      s13 = fmaf(qc.w, k3.w, fmaf(qc.z, k3.z, fmaf(qc.y, k3.y, fmaf(qc.x, k3.x, s13))));
    }

    // ---- online softmax (across 16 mg-lanes)
    float rm0 = fmaxf(fmaxf(s00, s01), fmaxf(s02, s03));
    rm0 = fmaxf(rm0, __shfl_xor(rm0, 1));
    rm0 = fmaxf(rm0, __shfl_xor(rm0, 2));
    rm0 = fmaxf(rm0, __shfl_xor(rm0, 4));
    rm0 = fmaxf(rm0, __shfl_xor(rm0, 8));
    float rm1 = fmaxf(fmaxf(s10, s11), fmaxf(s12, s13));
    rm1 = fmaxf(rm1, __shfl_xor(rm1, 1));
    rm1 = fmaxf(rm1, __shfl_xor(rm1, 2));
    rm1 = fmaxf(rm1, __shfl_xor(rm1, 4));
    rm1 = fmaxf(rm1, __shfl_xor(rm1, 8));

    const float mn0 = fmaxf(m0r, rm0);
    const float mn1 = fmaxf(m1r, rm1);
    const float al0 = __expf(m0r - mn0);
    const float al1 = __expf(m1r - mn1);
    m0r = mn0; m1r = mn1;

    const float p00 = __expf(s00 - mn0), p01 = __expf(s01 - mn0);
    const float p02 = __expf(s02 - mn0), p03 = __expf(s03 - mn0);
    const float p10 = __expf(s10 - mn1), p11 = __expf(s11 - mn1);
    const float p12 = __expf(s12 - mn1), p13 = __expf(s13 - mn1);

    float rs0 = p00 + p01 + p02 + p03;
    rs0 += __shfl_xor(rs0, 1);
    rs0 += __shfl_xor(rs0, 2);
    rs0 += __shfl_xor(rs0, 4);
    rs0 += __shfl_xor(rs0, 8);
    float rs1 = p10 + p11 + p12 + p13;
    rs1 += __shfl_xor(rs1, 1);
    rs1 += __shfl_xor(rs1, 2);
    rs1 += __shfl_xor(rs1, 4);
    rs1 += __shfl_xor(rs1, 8);
    l0 = al0 * l0 + rs0;
    l1 = al1 * l1 + rs1;

    // ---- exchange P through LDS (prev tile's PV reads must be done)
    __syncthreads();
    *(float4*)(prow0 + 4 * mg) = make_float4(p00, p01, p02, p03);
    *(float4*)(prow1 + 4 * mg) = make_float4(p10, p11, p12, p13);
    __syncthreads();

    // ---- rescale O
    o0.x *= al0; o0.y *= al0; o0.z *= al0; o0.w *= al0;
    o1.x *= al1; o1.y *= al1; o1.z *= al1; o1.w *= al1;

    // ---- PV: o[i][j] += sum_m P[row_i][m] * V[m][4mg+j]
    #pragma unroll
    for (int m4 = 0; m4 < 16; ++m4) {
      const float4 pa = *(const float4*)(prow0 + m4 * 4);   // broadcast read
      const float4 pc = *(const float4*)(prow1 + m4 * 4);
      const float4 v0 = *(const float4*)(vpt + (m4 * 4 + 0) * 64);
      const float4 v1 = *(const float4*)(vpt + (m4 * 4 + 1) * 64);
      const float4 v2 = *(const float4*)(vpt + (m4 * 4 + 2) * 64);
      const float4 v3 = *(const float4*)(vpt + (m4 * 4 + 3) * 64);
      o0.x = fmaf(pa.w, v3.x, fmaf(pa.z, v2.x, fmaf(pa.y, v1.x, fmaf(pa.x, v0.x, o0.x))));
      o0.y = fmaf(pa.w, v3.y, fmaf(pa.z, v2.y, fmaf(pa.y, v1.y, fmaf(pa.x, v0.y, o0.y))));
      o0.z = fmaf(pa.w, v3.z, fmaf(pa.z, v2.z, fmaf(pa.y, v1.z, fmaf(pa.x, v0.z, o0.z))));
      o0.w = fmaf(pa.w, v3.w, fmaf(pa.z, v2.w, fmaf(pa.y, v1.w, fmaf(pa.x, v0.w, o0.w))));
      o1.x = fmaf(pc.w, v3.x, fmaf(pc.z, v2.x, fmaf(pc.y, v1.x, fmaf(pc.x, v0.x, o1.x))));
      o1.y = fmaf(pc.w, v3.y, fmaf(pc.z, v2.y, fmaf(pc.y, v1.y, fmaf(pc.x, v0.y, o1.y))));
      o1.z = fmaf(pc.w, v3.z, fmaf(pc.z, v2.z, fmaf(pc.y, v1.z, fmaf(pc.x, v0.z, o1.z))));
      o1.w = fmaf(pc.w, v3.w, fmaf(pc.z, v2.w, fmaf(pc.y, v1.w, fmaf(pc.x, v0.w, o1.w))));
    }
  }

  // ---- epilogue: normalize, transpose through smem ([64 c][36]), store
  const float inv0 = 1.f / l0;
  const float inv1 = 1.f / l1;
  __syncthreads();   // all PV reads done; smem free for reuse
  {
    const int c0 = 4 * mg;
    smem[(c0 + 0) * 36 + 2 * ng + 0] = o0.x * inv0;
    smem[(c0 + 1) * 36 + 2 * ng + 0] = o0.y * inv0;
    smem[(c0 + 2) * 36 + 2 * ng + 0] = o0.z * inv0;
    smem[(c0 + 3) * 36 + 2 * ng + 0] = o0.w * inv0;
    smem[(c0 + 0) * 36 + 2 * ng + 1] = o1.x * inv1;
    smem[(c0 + 1) * 36 + 2 * ng + 1] = o1.y * inv1;
    smem[(c0 + 2) * 36 + 2 * ng + 1] = o1.z * inv1;
    smem[(c0 + 3) * 36 + 2 * ng + 1] = o1.w * inv1;
  }
  __syncthreads();
  {
    const int c = t >> 2;   // 0..63
    #pragma unroll
    for (int r = 0; r < 2; ++r) {
      const int f4i = (t & 3) + 4 * r;   // 0..7
      *(float4*)(f + ((size_t)b * 64 + c) * 4096 + n0 + f4i * 4) =
          *(const float4*)(smem + c * 36 + f4i * 4);
    }
  }
}

// ---------------------------------------------------------------------------
// conv_r (unchanged from R19/R22; fin is [b][64 c][4096 px]).
__global__ __launch_bounds__(256, 4) void conv_r_f32(
    const float* __restrict__ fin, const float* __restrict__ w,
    const float* __restrict__ bi, const float* __restrict__ g,
    const float* __restrict__ be, const float* __restrict__ mu,
    const float* __restrict__ va, const float* __restrict__ res,
    float* __restrict__ out)
{
  __shared__ float tA[2][CTSZ];
  __shared__ float wlds[80];

  const int b   = blockIdx.z;
  const int co0 = blockIdx.y * 4;
  const int y0  = blockIdx.x * 16;
  const int t   = threadIdx.x;
  const int ry  = t >> 4;
  const int xg  = t & 15;
  const int x0  = xg * 4;

  float sc[4], sh[4];
  #pragma unroll
  for (int cc = 0; cc < 4; ++cc) {
    const int c = co0 + cc;
    const float iv = g[c] * rsqrtf(va[c] + 1e-5f);
    sc[cc] = iv; sh[cc] = bi[c] * iv + be[c] - mu[c] * iv;
  }

  const float* srcA = fin + (size_t)b * 64 * 4096;
  float4 rA[2][2];
  const int row0 = t >> 4;
  const int row1 = 16 + (t >> 4);
  const int grp  = t & 15;

  const int wseg = t / 18;
  const int wkk  = t - wseg * 18;
  const int wbase0 = (co0 + wseg) * 64 * 9 + wkk;
  float wreg = 0.f;

  #define LOADR(R)                                                            \
    {                                                                         \
      _Pragma("unroll")                                                       \
      for (int s = 0; s < 2; ++s) {                                           \
        const size_t cb = (size_t)((R) * 2 + s) * 4096;                       \
        {                                                                     \
          const int gy = y0 - 1 + row0;                                       \
          float4 a = make_float4(0.f, 0.f, 0.f, 0.f);                         \
          if (gy >= 0 && gy <= 63)                                            \
            a = *(const float4*)(srcA + cb + gy * 64 + grp * 4);              \
          rA[s][0] = a;                                                       \
        }                                                                     \
        if (t < 32) {                                                         \
          const int gy = y0 - 1 + row1;                                       \
          float4 a = make_float4(0.f, 0.f, 0.f, 0.f);                         \
          if (gy >= 0 && gy <= 63)                                            \
            a = *(const float4*)(srcA + cb + gy * 64 + grp * 4);              \
          rA[s][1] = a;                                                       \
        }                                                                     \
      }                                                                       \
      if (t < 72) wreg = w[wbase0 + (R) * 18];                                \
    }

  float acc[4][4] = {{0.f}};
  LOADR(0);

  for (int r = 0; r < 32; ++r) {
    __syncthreads();
    #pragma unroll
    for (int s = 0; s < 2; ++s) {
      *(float4*)(&tA[s][row0 * CTSTR + grp * 4]) = rA[s][0];
      if (t < 32)
        *(float4*)(&tA[s][row1 * CTSTR + grp * 4]) = rA[s][1];
    }
    if (t < 72) wlds[t] = wreg;
    __syncthreads();
    if (r < 31) LOADR(r + 1);

    #pragma unroll
    for (int s = 0; s < 2; ++s) {
      #pragma unroll
      for (int ky = 0; ky < 3; ++ky) {
        const float4 a4 = *(const float4*)(&tA[s][(ry + ky) * CTSTR + x0]);
        const float ca[6] = {dpp_left(a4.w), a4.x, a4.y, a4.z, a4.w, dpp_right(a4.x)};
        #pragma unroll
        for (int cc = 0; cc < 4; ++cc) {
          const int wb = cc * 18 + s * 9 + ky * 3;
          const float w0 = wlds[wb], w1 = wlds[wb + 1], w2 = wlds[wb + 2];
          #pragma unroll
          for (int px = 0; px < 4; ++px)
            acc[cc][px] += ca[px] * w0 + ca[px + 1] * w1 + ca[px + 2] * w2;
        }
      }
    }
  }

  const size_t ob = ((size_t)b * 256 + co0) * 4096 + (size_t)(y0 + ry) * 64 + x0;
  #pragma unroll
  for (int cc = 0; cc < 4; ++cc) {
    const float4 rv = *(const float4*)(res + ob + (size_t)cc * 4096);
    float4 o;
    o.x = rv.x + fmaxf(acc[cc][0] * sc[cc] + sh[cc], 0.f);
    o.y = rv.y + fmaxf(acc[cc][1] * sc[cc] + sh[cc], 0.f);
    o.z = rv.z + fmaxf(acc[cc][2] * sc[cc] + sh[cc], 0.f);
    o.w = rv.w + fmaxf(acc[cc][3] * sc[cc] + sh[cc], 0.f);
    *(float4*)(out + ob + (size_t)cc * 4096) = o;
  }
}

// ---------------------------------------------------------------------------
extern "C" void kernel_launch(void* const* d_in, const int* in_sizes, int n_in,
                              void* d_out, int out_size, void* d_ws, size_t ws_size,
                              hipStream_t stream) {
  const float* f1 = (const float*)d_in[0];
  const float* f2 = (const float*)d_in[1];
  const float* qw = (const float*)d_in[2];  const float* qb = (const float*)d_in[3];
  const float* qg = (const float*)d_in[4];  const float* qbe = (const float*)d_in[5];
  const float* qm = (const float*)d_in[6];  const float* qv = (const float*)d_in[7];
  const float* kw = (const float*)d_in[8];  const float* kb = (const float*)d_in[9];
  const float* kg = (const float*)d_in[10]; const float* kbe = (const float*)d_in[11];
  const float* km = (const float*)d_in[12]; const float* kv = (const float*)d_in[13];
  const float* vw = (const float*)d_in[14]; const float* vb = (const float*)d_in[15];
  const float* vg = (const float*)d_in[16]; const float* vbe = (const float*)d_in[17];
  const float* vm = (const float*)d_in[18]; const float* vv = (const float*)d_in[19];
  const float* rw = (const float*)d_in[20]; const float* rb = (const float*)d_in[21];
  const float* rg = (const float*)d_in[22]; const float* rbe = (const float*)d_in[23];
  const float* rm = (const float*)d_in[24]; const float* rv = (const float*)d_in[25];

  hipStreamCaptureStatus cap = hipStreamCaptureStatusNone;
  unsigned long long capid = 0;
  const hipError_t ce = hipStreamGetCaptureInfo(stream, &cap, &capid);
  const bool capturing = (ce == hipSuccess) && (cap != hipStreamCaptureStatusNone);

  // Workspace: q,k,v (pixel-major) + f (channel-major), 4 MB each.
  const size_t SZ1 = (size_t)4 * 64 * 4096 * 4;
  float* qp = (float*)d_ws;
  float* kp = (float*)((char*)d_ws + SZ1);
  float* vp = (float*)((char*)d_ws + 2 * SZ1);
  float* fp = (float*)((char*)d_ws + 3 * SZ1);

  convqkv_f32<<<dim3(4, 32, 4), 256, 0, stream>>>(
      f1, f2,
      qw, qb, qg, qbe, qm, qv,
      kw, kb, kg, kbe, km, kv,
      vw, vb, vg, vbe, vm, vv,
      qp, kp, vp);
  attention_flash_f32<<<dim3(512), 256, 0, stream>>>(qp, kp, vp, fp);
  conv_r_f32<<<dim3(4, 64, 4), 256, 0, stream>>>(fp, rw, rb, rg, rbe, rm, rv,
                                                 f1, (float*)d_out);

  if (!capturing) {
    const hipError_t le = hipGetLastError();
    const hipError_t se = hipStreamSynchronize(stream);
    float h[4] = {0, 0, 0, 0};
    (void)hipMemcpy(h, d_out, 16, hipMemcpyDeviceToHost);
    fprintf(stderr,
        "ATHENA_R23 smallO-directKV le=%d sync=%d out=[%g %g %g %g]\n",
        (int)le, (int)se, h[0], h[1], h[2], h[3]);
    fflush(stderr);
  }
}